// Round 2
// baseline (205.535 us; speedup 1.0000x reference)
//
#include <hip/hip_runtime.h>
#include <math.h>

#define D_MODEL 300
#define LSEQ    512
#define NBATCH  300
#define SPLIT   16
#define LCH     (LSEQ / SPLIT)      // 32 l-values per block
#define NG      4                   // parallel l-streams (groups) per block
#define LPG     (LCH / NG)          // 8 l-values per stream (= one full load batch)
#define NR      75                  // float4 lanes per row (75*4 = 300)
#define KCH     (D_MODEL / 4)       // 75, fc1 k-chunk
#define JPB     2                   // j-rows per fc1 block
#define TI      6                   // i-rows per termB block (300 = 50*6)
#define SCALE   17.32050807568877f  // sqrt(300)

// pe[l, e]: e even -> sin(l * div[e/2]); e odd -> cos(l * div[e/2])
__global__ void pe_kernel(float* __restrict__ pe) {
    int idx = blockIdx.x * blockDim.x + threadIdx.x;
    if (idx >= LSEQ * D_MODEL) return;
    int l = idx / D_MODEL;
    int e = idx - l * D_MODEL;
    int k = e >> 1;
    float dv = expf((float)(2 * k) * (-9.210340371976184f / 300.0f));
    float arg = (float)l * dv;
    pe[idx] = (e & 1) ? cosf(arg) : sinf(arg);
}

// S[i][l] = emb2[x2[i,l]][i]*SCALE + pe[l][i]  (the diag weight vector per i)
// Pure scatter-gather, fully parallel: one thread per (i,l).
__global__ void s_kernel(const int* __restrict__ x2, const float* __restrict__ emb2,
                         const float* __restrict__ pe, float* __restrict__ S) {
    int idx = blockIdx.x * blockDim.x + threadIdx.x;  // i*LSEQ + l
    if (idx >= NBATCH * LSEQ) return;
    int i = idx >> 9;            // / 512
    int l = idx & (LSEQ - 1);
    int v = x2[idx];
    S[idx] = emb2[(size_t)v * D_MODEL + i] * SCALE + pe[l * D_MODEL + i];
}

// Term A: Dm[i][e] += SCALE * sum_{l in chunk} S[i][l] * emb1[x1[i,l]][e]
// No pe reads in the hot loop -> demand traffic halved vs fused version.
// 8 independent float4 gathers per thread, fully unrolled.
__global__ void diagA_kernel(const int* __restrict__ x1, const float* __restrict__ S,
                             const float* __restrict__ emb1, float* __restrict__ Dm) {
    __shared__ int    x1ch[LCH];
    __shared__ float  sch[LCH];
    __shared__ float4 part[NG][NR];
    const int i   = blockIdx.x;   // batch index (== diagonal index)
    const int sp  = blockIdx.y;   // l-chunk
    const int tid = threadIdx.x;
    const int l0  = sp * LCH;

    if (tid < LCH) {
        x1ch[tid] = x1[i * LSEQ + l0 + tid];
        sch[tid]  = S[i * LSEQ + l0 + tid] * SCALE;   // fold term-A SCALE here
    }
    __syncthreads();

    const int g = tid / NR;       // l-stream
    const int r = tid - g * NR;   // float4 index within row

    if (tid < NG * NR) {
        const int lb = g * LPG;   // this stream owns l0+lb .. l0+lb+7
        const float4 v0 = ((const float4*)(emb1 + (size_t)x1ch[lb + 0] * D_MODEL))[r];
        const float4 v1 = ((const float4*)(emb1 + (size_t)x1ch[lb + 1] * D_MODEL))[r];
        const float4 v2 = ((const float4*)(emb1 + (size_t)x1ch[lb + 2] * D_MODEL))[r];
        const float4 v3 = ((const float4*)(emb1 + (size_t)x1ch[lb + 3] * D_MODEL))[r];
        const float4 v4 = ((const float4*)(emb1 + (size_t)x1ch[lb + 4] * D_MODEL))[r];
        const float4 v5 = ((const float4*)(emb1 + (size_t)x1ch[lb + 5] * D_MODEL))[r];
        const float4 v6 = ((const float4*)(emb1 + (size_t)x1ch[lb + 6] * D_MODEL))[r];
        const float4 v7 = ((const float4*)(emb1 + (size_t)x1ch[lb + 7] * D_MODEL))[r];
        const float s0 = sch[lb + 0], s1 = sch[lb + 1], s2 = sch[lb + 2], s3 = sch[lb + 3];
        const float s4 = sch[lb + 4], s5 = sch[lb + 5], s6 = sch[lb + 6], s7 = sch[lb + 7];
        float ax, ay, az, aw;
        ax = s0 * v0.x;            ay = s0 * v0.y;            az = s0 * v0.z;            aw = s0 * v0.w;
        ax = fmaf(s1, v1.x, ax);   ay = fmaf(s1, v1.y, ay);   az = fmaf(s1, v1.z, az);   aw = fmaf(s1, v1.w, aw);
        ax = fmaf(s2, v2.x, ax);   ay = fmaf(s2, v2.y, ay);   az = fmaf(s2, v2.z, az);   aw = fmaf(s2, v2.w, aw);
        ax = fmaf(s3, v3.x, ax);   ay = fmaf(s3, v3.y, ay);   az = fmaf(s3, v3.z, az);   aw = fmaf(s3, v3.w, aw);
        ax = fmaf(s4, v4.x, ax);   ay = fmaf(s4, v4.y, ay);   az = fmaf(s4, v4.z, az);   aw = fmaf(s4, v4.w, aw);
        ax = fmaf(s5, v5.x, ax);   ay = fmaf(s5, v5.y, ay);   az = fmaf(s5, v5.z, az);   aw = fmaf(s5, v5.w, aw);
        ax = fmaf(s6, v6.x, ax);   ay = fmaf(s6, v6.y, ay);   az = fmaf(s6, v6.z, az);   aw = fmaf(s6, v6.w, aw);
        ax = fmaf(s7, v7.x, ax);   ay = fmaf(s7, v7.y, ay);   az = fmaf(s7, v7.z, az);   aw = fmaf(s7, v7.w, aw);
        part[g][r] = make_float4(ax, ay, az, aw);
    }
    __syncthreads();

    if (g == 0 && tid < NR) {
        float4 p0 = part[0][r], p1 = part[1][r], p2 = part[2][r], p3 = part[3][r];
        float* dst = Dm + i * D_MODEL + 4 * r;
        atomicAdd(dst + 0, p0.x + p1.x + p2.x + p3.x);
        atomicAdd(dst + 1, p0.y + p1.y + p2.y + p3.y);
        atomicAdd(dst + 2, p0.z + p1.z + p2.z + p3.z);
        atomicAdd(dst + 3, p0.w + p1.w + p2.w + p3.w);
    }
}

// Term B: Dm[i][e] += sum_l S[i][l] * pe[l][e]   -- a [300,512]@[512,300] GEMM,
// tiled TI i-rows per block so pe is read 50x (31 MB from cache) not 300x.
__global__ void termB_kernel(const float* __restrict__ S, const float* __restrict__ pe,
                             float* __restrict__ Dm) {
    __shared__ float sS[TI][LSEQ];   // 6*512*4 = 12 KB
    const int i0  = blockIdx.x * TI;
    const int tid = threadIdx.x;

    for (int t = tid; t < TI * LSEQ; t += 320) {
        int ti = t >> 9;
        int l  = t & (LSEQ - 1);
        sS[ti][l] = S[(i0 + ti) * LSEQ + l];
    }
    __syncthreads();

    if (tid < D_MODEL) {
        float acc0 = 0.f, acc1 = 0.f, acc2 = 0.f, acc3 = 0.f, acc4 = 0.f, acc5 = 0.f;
        for (int l = 0; l < LSEQ; l += 4) {
            float p0 = pe[(l + 0) * D_MODEL + tid];
            float p1 = pe[(l + 1) * D_MODEL + tid];
            float p2 = pe[(l + 2) * D_MODEL + tid];
            float p3 = pe[(l + 3) * D_MODEL + tid];
            acc0 = fmaf(sS[0][l + 0], p0, acc0); acc0 = fmaf(sS[0][l + 1], p1, acc0);
            acc0 = fmaf(sS[0][l + 2], p2, acc0); acc0 = fmaf(sS[0][l + 3], p3, acc0);
            acc1 = fmaf(sS[1][l + 0], p0, acc1); acc1 = fmaf(sS[1][l + 1], p1, acc1);
            acc1 = fmaf(sS[1][l + 2], p2, acc1); acc1 = fmaf(sS[1][l + 3], p3, acc1);
            acc2 = fmaf(sS[2][l + 0], p0, acc2); acc2 = fmaf(sS[2][l + 1], p1, acc2);
            acc2 = fmaf(sS[2][l + 2], p2, acc2); acc2 = fmaf(sS[2][l + 3], p3, acc2);
            acc3 = fmaf(sS[3][l + 0], p0, acc3); acc3 = fmaf(sS[3][l + 1], p1, acc3);
            acc3 = fmaf(sS[3][l + 2], p2, acc3); acc3 = fmaf(sS[3][l + 3], p3, acc3);
            acc4 = fmaf(sS[4][l + 0], p0, acc4); acc4 = fmaf(sS[4][l + 1], p1, acc4);
            acc4 = fmaf(sS[4][l + 2], p2, acc4); acc4 = fmaf(sS[4][l + 3], p3, acc4);
            acc5 = fmaf(sS[5][l + 0], p0, acc5); acc5 = fmaf(sS[5][l + 1], p1, acc5);
            acc5 = fmaf(sS[5][l + 2], p2, acc5); acc5 = fmaf(sS[5][l + 3], p3, acc5);
        }
        atomicAdd(&Dm[(i0 + 0) * D_MODEL + tid], acc0);
        atomicAdd(&Dm[(i0 + 1) * D_MODEL + tid], acc1);
        atomicAdd(&Dm[(i0 + 2) * D_MODEL + tid], acc2);
        atomicAdd(&Dm[(i0 + 3) * D_MODEL + tid], acc3);
        atomicAdd(&Dm[(i0 + 4) * D_MODEL + tid], acc4);
        atomicAdd(&Dm[(i0 + 5) * D_MODEL + tid], acc5);
    }
}

// fc1 k-split partial, JPB j-rows per block for Dm reuse:
// Hpre[j][e] += sum_{k in chunk} w1[j,k] * Dm[k][e]
__global__ void fc1_kernel(const float* __restrict__ w1, const float* __restrict__ Dm,
                           float* __restrict__ Hpre) {
    const int j0  = blockIdx.x * JPB;
    const int sp  = blockIdx.y;
    const int tid = threadIdx.x;
    const int k0  = sp * KCH;
    if (tid >= D_MODEL) return;
    const float* w1r0 = w1 + (j0 + 0) * D_MODEL + k0;
    const float* w1r1 = w1 + (j0 + 1) * D_MODEL + k0;
    float acc0 = 0.0f, acc1 = 0.0f;
    #pragma unroll 5
    for (int k = 0; k < KCH; ++k) {
        float d = Dm[(k0 + k) * D_MODEL + tid];
        acc0 = fmaf(w1r0[k], d, acc0);
        acc1 = fmaf(w1r1[k], d, acc1);
    }
    atomicAdd(&Hpre[(j0 + 0) * D_MODEL + tid], acc0);
    atomicAdd(&Hpre[(j0 + 1) * D_MODEL + tid], acc1);
}

// Fused bias + relu + fc2 + softmax. Block = 256 thr = 64 e-lanes x 4 j-chunks.
__global__ void fc2_softmax_kernel(const float* __restrict__ Hpre, const float* __restrict__ b1,
                                   const float* __restrict__ w2, const float* __restrict__ b2,
                                   float* __restrict__ out) {
    __shared__ float sm[4][4][64];   // [jc][o][e_loc]
    const int tid   = threadIdx.x;
    const int e_loc = tid & 63;
    const int jc    = tid >> 6;
    const int e     = blockIdx.x * 64 + e_loc;

    float a0 = 0.f, a1 = 0.f, a2 = 0.f, a3 = 0.f;
    if (e < D_MODEL) {
        const int j0 = jc * 75;
        #pragma unroll 5
        for (int j = j0; j < j0 + 75; ++j) {
            float h = fmaxf(Hpre[j * D_MODEL + e] + b1[j], 0.0f);
            a0 = fmaf(h, w2[0 * D_MODEL + j], a0);
            a1 = fmaf(h, w2[1 * D_MODEL + j], a1);
            a2 = fmaf(h, w2[2 * D_MODEL + j], a2);
            a3 = fmaf(h, w2[3 * D_MODEL + j], a3);
        }
    }
    sm[jc][0][e_loc] = a0; sm[jc][1][e_loc] = a1;
    sm[jc][2][e_loc] = a2; sm[jc][3][e_loc] = a3;
    __syncthreads();

    if (jc == 0 && e < D_MODEL) {
        float l0 = b2[0] + sm[0][0][e_loc] + sm[1][0][e_loc] + sm[2][0][e_loc] + sm[3][0][e_loc];
        float l1 = b2[1] + sm[0][1][e_loc] + sm[1][1][e_loc] + sm[2][1][e_loc] + sm[3][1][e_loc];
        float l2 = b2[2] + sm[0][2][e_loc] + sm[1][2][e_loc] + sm[2][2][e_loc] + sm[3][2][e_loc];
        float l3 = b2[3] + sm[0][3][e_loc] + sm[1][3][e_loc] + sm[2][3][e_loc] + sm[3][3][e_loc];
        float m  = fmaxf(fmaxf(l0, l1), fmaxf(l2, l3));
        float x0 = expf(l0 - m), x1 = expf(l1 - m), x2 = expf(l2 - m), x3 = expf(l3 - m);
        float inv = 1.0f / (x0 + x1 + x2 + x3);
        out[e * 4 + 0] = x0 * inv;
        out[e * 4 + 1] = x1 * inv;
        out[e * 4 + 2] = x2 * inv;
        out[e * 4 + 3] = x3 * inv;
    }
}

extern "C" void kernel_launch(void* const* d_in, const int* in_sizes, int n_in,
                              void* d_out, int out_size, void* d_ws, size_t ws_size,
                              hipStream_t stream) {
    const int*   x1   = (const int*)d_in[0];
    const int*   x2   = (const int*)d_in[1];
    const float* emb1 = (const float*)d_in[2];
    const float* emb2 = (const float*)d_in[3];
    const float* w1   = (const float*)d_in[4];
    const float* b1   = (const float*)d_in[5];
    const float* w2   = (const float*)d_in[6];
    const float* b2   = (const float*)d_in[7];
    float* out = (float*)d_out;

    char* ws = (char*)d_ws;
    float* pe   = (float*)ws;                  // 512*300*4 = 614400 B
    float* Dm   = (float*)(ws + 614400);       // 300*300*4 = 360000 B
    float* Hpre = (float*)(ws + 974400);       // 300*300*4 = 360000 B
    float* S    = (float*)(ws + 1334400);      // 300*512*4 = 614400 B

    // zero the two atomic-accumulated buffers (contiguous)
    (void)hipMemsetAsync(Dm, 0, 2 * 360000, stream);

    pe_kernel<<<(LSEQ * D_MODEL + 255) / 256, 256, 0, stream>>>(pe);
    s_kernel<<<(NBATCH * LSEQ + 255) / 256, 256, 0, stream>>>(x2, emb2, pe, S);
    diagA_kernel<<<dim3(NBATCH, SPLIT), 320, 0, stream>>>(x1, S, emb1, Dm);
    termB_kernel<<<NBATCH / TI, 320, 0, stream>>>(S, pe, Dm);
    fc1_kernel<<<dim3(D_MODEL / JPB, 4), 320, 0, stream>>>(w1, Dm, Hpre);
    fc2_softmax_kernel<<<(D_MODEL + 63) / 64, 256, 0, stream>>>(Hpre, b1, w2, b2, out);
}

// Round 3
// 169.235 us; speedup vs baseline: 1.2145x; 1.2145x over previous
//
#include <hip/hip_runtime.h>
#include <math.h>

#define D_MODEL 300
#define LSEQ    512
#define NBATCH  300
#define SPLIT   16
#define LCH     (LSEQ / SPLIT)      // 32 l-values per block
#define NG      4                   // parallel l-streams (groups) per block
#define LPG     (LCH / NG)          // 8 l-values per stream (= one full load batch)
#define NR      75                  // float4 lanes per row (75*4 = 300)
#define KCH     (D_MODEL / 4)       // 75, fc1 k-chunk
#define JPB     2                   // j-rows per fc1 block
#define TI      6                   // i-rows per termB block (300 = 50*6)
#define SPLITB  16                  // l-splits for termB
#define LCHB    (LSEQ / SPLITB)     // 32 l-values per termB block
#define SCALE   17.32050807568877f  // sqrt(300)

// pe[l, e]: e even -> sin(l * div[e/2]); e odd -> cos(l * div[e/2])
__global__ void pe_kernel(float* __restrict__ pe) {
    int idx = blockIdx.x * blockDim.x + threadIdx.x;
    if (idx >= LSEQ * D_MODEL) return;
    int l = idx / D_MODEL;
    int e = idx - l * D_MODEL;
    int k = e >> 1;
    float dv = expf((float)(2 * k) * (-9.210340371976184f / 300.0f));
    float arg = (float)l * dv;
    pe[idx] = (e & 1) ? cosf(arg) : sinf(arg);
}

// S[i][l] = emb2[x2[i,l]][i]*SCALE + pe[l][i]  (the diag weight vector per i)
// Pure scatter-gather, fully parallel: one thread per (i,l).
__global__ void s_kernel(const int* __restrict__ x2, const float* __restrict__ emb2,
                         const float* __restrict__ pe, float* __restrict__ S) {
    int idx = blockIdx.x * blockDim.x + threadIdx.x;  // i*LSEQ + l
    if (idx >= NBATCH * LSEQ) return;
    int i = idx >> 9;            // / 512
    int l = idx & (LSEQ - 1);
    int v = x2[idx];
    S[idx] = emb2[(size_t)v * D_MODEL + i] * SCALE + pe[l * D_MODEL + i];
}

// Term A: Dm[i][e] += SCALE * sum_{l in chunk} S[i][l] * emb1[x1[i,l]][e]
// No pe reads in the hot loop. 8 independent float4 gathers per thread, fully unrolled.
__global__ void diagA_kernel(const int* __restrict__ x1, const float* __restrict__ S,
                             const float* __restrict__ emb1, float* __restrict__ Dm) {
    __shared__ int    x1ch[LCH];
    __shared__ float  sch[LCH];
    __shared__ float4 part[NG][NR];
    const int i   = blockIdx.x;   // batch index (== diagonal index)
    const int sp  = blockIdx.y;   // l-chunk
    const int tid = threadIdx.x;
    const int l0  = sp * LCH;

    if (tid < LCH) {
        x1ch[tid] = x1[i * LSEQ + l0 + tid];
        sch[tid]  = S[i * LSEQ + l0 + tid] * SCALE;   // fold term-A SCALE here
    }
    __syncthreads();

    const int g = tid / NR;       // l-stream
    const int r = tid - g * NR;   // float4 index within row

    if (tid < NG * NR) {
        const int lb = g * LPG;   // this stream owns l0+lb .. l0+lb+7
        const float4 v0 = ((const float4*)(emb1 + (size_t)x1ch[lb + 0] * D_MODEL))[r];
        const float4 v1 = ((const float4*)(emb1 + (size_t)x1ch[lb + 1] * D_MODEL))[r];
        const float4 v2 = ((const float4*)(emb1 + (size_t)x1ch[lb + 2] * D_MODEL))[r];
        const float4 v3 = ((const float4*)(emb1 + (size_t)x1ch[lb + 3] * D_MODEL))[r];
        const float4 v4 = ((const float4*)(emb1 + (size_t)x1ch[lb + 4] * D_MODEL))[r];
        const float4 v5 = ((const float4*)(emb1 + (size_t)x1ch[lb + 5] * D_MODEL))[r];
        const float4 v6 = ((const float4*)(emb1 + (size_t)x1ch[lb + 6] * D_MODEL))[r];
        const float4 v7 = ((const float4*)(emb1 + (size_t)x1ch[lb + 7] * D_MODEL))[r];
        const float s0 = sch[lb + 0], s1 = sch[lb + 1], s2 = sch[lb + 2], s3 = sch[lb + 3];
        const float s4 = sch[lb + 4], s5 = sch[lb + 5], s6 = sch[lb + 6], s7 = sch[lb + 7];
        float ax, ay, az, aw;
        ax = s0 * v0.x;            ay = s0 * v0.y;            az = s0 * v0.z;            aw = s0 * v0.w;
        ax = fmaf(s1, v1.x, ax);   ay = fmaf(s1, v1.y, ay);   az = fmaf(s1, v1.z, az);   aw = fmaf(s1, v1.w, aw);
        ax = fmaf(s2, v2.x, ax);   ay = fmaf(s2, v2.y, ay);   az = fmaf(s2, v2.z, az);   aw = fmaf(s2, v2.w, aw);
        ax = fmaf(s3, v3.x, ax);   ay = fmaf(s3, v3.y, ay);   az = fmaf(s3, v3.z, az);   aw = fmaf(s3, v3.w, aw);
        ax = fmaf(s4, v4.x, ax);   ay = fmaf(s4, v4.y, ay);   az = fmaf(s4, v4.z, az);   aw = fmaf(s4, v4.w, aw);
        ax = fmaf(s5, v5.x, ax);   ay = fmaf(s5, v5.y, ay);   az = fmaf(s5, v5.z, az);   aw = fmaf(s5, v5.w, aw);
        ax = fmaf(s6, v6.x, ax);   ay = fmaf(s6, v6.y, ay);   az = fmaf(s6, v6.z, az);   aw = fmaf(s6, v6.w, aw);
        ax = fmaf(s7, v7.x, ax);   ay = fmaf(s7, v7.y, ay);   az = fmaf(s7, v7.z, az);   aw = fmaf(s7, v7.w, aw);
        part[g][r] = make_float4(ax, ay, az, aw);
    }
    __syncthreads();

    if (g == 0 && tid < NR) {
        float4 p0 = part[0][r], p1 = part[1][r], p2 = part[2][r], p3 = part[3][r];
        float* dst = Dm + i * D_MODEL + 4 * r;
        atomicAdd(dst + 0, p0.x + p1.x + p2.x + p3.x);
        atomicAdd(dst + 1, p0.y + p1.y + p2.y + p3.y);
        atomicAdd(dst + 2, p0.z + p1.z + p2.z + p3.z);
        atomicAdd(dst + 3, p0.w + p1.w + p2.w + p3.w);
    }
}

// Term B: Dm[i][e] += sum_l S[i][l] * pe[l][e]   -- [300,512]@[512,300] GEMM.
// v2: l-dim split 16-ways -> 800 blocks (was 50); pe rows are L2-resident,
// latency hidden by ~15 waves/CU instead of ~1.
__global__ void termB_kernel(const float* __restrict__ S, const float* __restrict__ pe,
                             float* __restrict__ Dm) {
    __shared__ float sS[TI][LCHB];   // 6*32*4 = 768 B
    const int i0  = blockIdx.x * TI;
    const int l0  = blockIdx.y * LCHB;
    const int tid = threadIdx.x;

    if (tid < TI * LCHB) {
        int ti = tid >> 5;           // / LCHB
        int l  = tid & (LCHB - 1);
        sS[ti][l] = S[(i0 + ti) * LSEQ + l0 + l];
    }
    __syncthreads();

    if (tid < D_MODEL) {
        float acc0 = 0.f, acc1 = 0.f, acc2 = 0.f, acc3 = 0.f, acc4 = 0.f, acc5 = 0.f;
        #pragma unroll
        for (int l = 0; l < LCHB; l += 4) {
            float p0 = pe[(l0 + l + 0) * D_MODEL + tid];
            float p1 = pe[(l0 + l + 1) * D_MODEL + tid];
            float p2 = pe[(l0 + l + 2) * D_MODEL + tid];
            float p3 = pe[(l0 + l + 3) * D_MODEL + tid];
            acc0 = fmaf(sS[0][l + 0], p0, acc0); acc0 = fmaf(sS[0][l + 1], p1, acc0);
            acc0 = fmaf(sS[0][l + 2], p2, acc0); acc0 = fmaf(sS[0][l + 3], p3, acc0);
            acc1 = fmaf(sS[1][l + 0], p0, acc1); acc1 = fmaf(sS[1][l + 1], p1, acc1);
            acc1 = fmaf(sS[1][l + 2], p2, acc1); acc1 = fmaf(sS[1][l + 3], p3, acc1);
            acc2 = fmaf(sS[2][l + 0], p0, acc2); acc2 = fmaf(sS[2][l + 1], p1, acc2);
            acc2 = fmaf(sS[2][l + 2], p2, acc2); acc2 = fmaf(sS[2][l + 3], p3, acc2);
            acc3 = fmaf(sS[3][l + 0], p0, acc3); acc3 = fmaf(sS[3][l + 1], p1, acc3);
            acc3 = fmaf(sS[3][l + 2], p2, acc3); acc3 = fmaf(sS[3][l + 3], p3, acc3);
            acc4 = fmaf(sS[4][l + 0], p0, acc4); acc4 = fmaf(sS[4][l + 1], p1, acc4);
            acc4 = fmaf(sS[4][l + 2], p2, acc4); acc4 = fmaf(sS[4][l + 3], p3, acc4);
            acc5 = fmaf(sS[5][l + 0], p0, acc5); acc5 = fmaf(sS[5][l + 1], p1, acc5);
            acc5 = fmaf(sS[5][l + 2], p2, acc5); acc5 = fmaf(sS[5][l + 3], p3, acc5);
        }
        atomicAdd(&Dm[(i0 + 0) * D_MODEL + tid], acc0);
        atomicAdd(&Dm[(i0 + 1) * D_MODEL + tid], acc1);
        atomicAdd(&Dm[(i0 + 2) * D_MODEL + tid], acc2);
        atomicAdd(&Dm[(i0 + 3) * D_MODEL + tid], acc3);
        atomicAdd(&Dm[(i0 + 4) * D_MODEL + tid], acc4);
        atomicAdd(&Dm[(i0 + 5) * D_MODEL + tid], acc5);
    }
}

// fc1 k-split partial, JPB j-rows per block for Dm reuse:
// Hpre[j][e] += sum_{k in chunk} w1[j,k] * Dm[k][e]
__global__ void fc1_kernel(const float* __restrict__ w1, const float* __restrict__ Dm,
                           float* __restrict__ Hpre) {
    const int j0  = blockIdx.x * JPB;
    const int sp  = blockIdx.y;
    const int tid = threadIdx.x;
    const int k0  = sp * KCH;
    if (tid >= D_MODEL) return;
    const float* w1r0 = w1 + (j0 + 0) * D_MODEL + k0;
    const float* w1r1 = w1 + (j0 + 1) * D_MODEL + k0;
    float acc0 = 0.0f, acc1 = 0.0f;
    #pragma unroll 5
    for (int k = 0; k < KCH; ++k) {
        float d = Dm[(k0 + k) * D_MODEL + tid];
        acc0 = fmaf(w1r0[k], d, acc0);
        acc1 = fmaf(w1r1[k], d, acc1);
    }
    atomicAdd(&Hpre[(j0 + 0) * D_MODEL + tid], acc0);
    atomicAdd(&Hpre[(j0 + 1) * D_MODEL + tid], acc1);
}

// Fused bias + relu + fc2 + softmax. Block = 256 thr = 64 e-lanes x 4 j-chunks.
__global__ void fc2_softmax_kernel(const float* __restrict__ Hpre, const float* __restrict__ b1,
                                   const float* __restrict__ w2, const float* __restrict__ b2,
                                   float* __restrict__ out) {
    __shared__ float sm[4][4][64];   // [jc][o][e_loc]
    const int tid   = threadIdx.x;
    const int e_loc = tid & 63;
    const int jc    = tid >> 6;
    const int e     = blockIdx.x * 64 + e_loc;

    float a0 = 0.f, a1 = 0.f, a2 = 0.f, a3 = 0.f;
    if (e < D_MODEL) {
        const int j0 = jc * 75;
        #pragma unroll 5
        for (int j = j0; j < j0 + 75; ++j) {
            float h = fmaxf(Hpre[j * D_MODEL + e] + b1[j], 0.0f);
            a0 = fmaf(h, w2[0 * D_MODEL + j], a0);
            a1 = fmaf(h, w2[1 * D_MODEL + j], a1);
            a2 = fmaf(h, w2[2 * D_MODEL + j], a2);
            a3 = fmaf(h, w2[3 * D_MODEL + j], a3);
        }
    }
    sm[jc][0][e_loc] = a0; sm[jc][1][e_loc] = a1;
    sm[jc][2][e_loc] = a2; sm[jc][3][e_loc] = a3;
    __syncthreads();

    if (jc == 0 && e < D_MODEL) {
        float l0 = b2[0] + sm[0][0][e_loc] + sm[1][0][e_loc] + sm[2][0][e_loc] + sm[3][0][e_loc];
        float l1 = b2[1] + sm[0][1][e_loc] + sm[1][1][e_loc] + sm[2][1][e_loc] + sm[3][1][e_loc];
        float l2 = b2[2] + sm[0][2][e_loc] + sm[1][2][e_loc] + sm[2][2][e_loc] + sm[3][2][e_loc];
        float l3 = b2[3] + sm[0][3][e_loc] + sm[1][3][e_loc] + sm[2][3][e_loc] + sm[3][3][e_loc];
        float m  = fmaxf(fmaxf(l0, l1), fmaxf(l2, l3));
        float x0 = expf(l0 - m), x1 = expf(l1 - m), x2 = expf(l2 - m), x3 = expf(l3 - m);
        float inv = 1.0f / (x0 + x1 + x2 + x3);
        out[e * 4 + 0] = x0 * inv;
        out[e * 4 + 1] = x1 * inv;
        out[e * 4 + 2] = x2 * inv;
        out[e * 4 + 3] = x3 * inv;
    }
}

extern "C" void kernel_launch(void* const* d_in, const int* in_sizes, int n_in,
                              void* d_out, int out_size, void* d_ws, size_t ws_size,
                              hipStream_t stream) {
    const int*   x1   = (const int*)d_in[0];
    const int*   x2   = (const int*)d_in[1];
    const float* emb1 = (const float*)d_in[2];
    const float* emb2 = (const float*)d_in[3];
    const float* w1   = (const float*)d_in[4];
    const float* b1   = (const float*)d_in[5];
    const float* w2   = (const float*)d_in[6];
    const float* b2   = (const float*)d_in[7];
    float* out = (float*)d_out;

    char* ws = (char*)d_ws;
    float* pe   = (float*)ws;                  // 512*300*4 = 614400 B
    float* Dm   = (float*)(ws + 614400);       // 300*300*4 = 360000 B
    float* Hpre = (float*)(ws + 974400);       // 300*300*4 = 360000 B
    float* S    = (float*)(ws + 1334400);      // 300*512*4 = 614400 B

    // zero the two atomic-accumulated buffers (contiguous)
    (void)hipMemsetAsync(Dm, 0, 2 * 360000, stream);

    pe_kernel<<<(LSEQ * D_MODEL + 255) / 256, 256, 0, stream>>>(pe);
    s_kernel<<<(NBATCH * LSEQ + 255) / 256, 256, 0, stream>>>(x2, emb2, pe, S);
    diagA_kernel<<<dim3(NBATCH, SPLIT), 320, 0, stream>>>(x1, S, emb1, Dm);
    termB_kernel<<<dim3(NBATCH / TI, SPLITB), 320, 0, stream>>>(S, pe, Dm);
    fc1_kernel<<<dim3(D_MODEL / JPB, 4), 320, 0, stream>>>(w1, Dm, Hpre);
    fc2_softmax_kernel<<<(D_MODEL + 63) / 64, 256, 0, stream>>>(Hpre, b1, w2, b2, out);
}